// Round 1
// baseline (745.625 us; speedup 1.0000x reference)
//
#include <hip/hip_runtime.h>
#include <hip/hip_bf16.h>

#define E_TOTAL   800000
#define NN        50000
#define DD        128
#define DE        64
#define ZDIM      320
#define MT        64

typedef short bf16x8 __attribute__((ext_vector_type(8)));
typedef float f32x4  __attribute__((ext_vector_type(4)));

__device__ __forceinline__ unsigned short f2bf(float f) {
    union { float f; unsigned int u; } v; v.f = f;
    unsigned int u = v.u;
    return (unsigned short)((u + 0x7fffu + ((u >> 16) & 1u)) >> 16);
}

// out <- x ; Wt[n][k] = bf16(concat(W_f, W_s)^T)
__global__ void prep_kernel(const float* __restrict__ x,
                            const float* __restrict__ W_f,
                            const float* __restrict__ W_s,
                            unsigned short* __restrict__ Wt,
                            float* __restrict__ out) {
    int id = blockIdx.x * 256 + threadIdx.x;
    if (id < NN * DD / 4)
        ((float4*)out)[id] = ((const float4*)x)[id];
    if (id < 2 * DD * ZDIM) {
        int n = id / ZDIM, k = id - n * ZDIM;
        float wv = (n < DD) ? W_f[k * DD + n] : W_s[k * DD + (n - DD)];
        Wt[n * ZDIM + k] = f2bf(wv);
    }
}

// Fused gather + dual-GEMM + gated activation + scatter-add.
// Block: 256 thr (4 waves), 64 edges, N=256 (f||s), K=320 in 5 chunks of 64.
// LDS swizzle: 8-bf16 group g of row r stored at (g&~7)|((g&7)^(r&7)).
__global__ __launch_bounds__(256, 2)
void edge_kernel(const float* __restrict__ x,
                 const int* __restrict__ ei,
                 const float* __restrict__ ea,
                 const unsigned short* __restrict__ Wt,
                 const float* __restrict__ bf_,
                 const float* __restrict__ bs_,
                 float* __restrict__ out) {
    __shared__ unsigned short A_lds[MT * ZDIM];   // 40960 B
    __shared__ unsigned short B_lds[256 * 64];    // 32768 B
    __shared__ int dst_lds[MT];
    __shared__ int src_lds[MT];

    const int t = threadIdx.x;
    const int m_off = blockIdx.x * MT;
    const int lane = t & 63;
    const int w = t >> 6;
    const int l15 = lane & 15;
    const int quad = lane >> 4;

    if (t < MT) dst_lds[t] = ei[E_TOTAL + m_off + t];
    else if (t < 2 * MT) src_lds[t - MT] = ei[m_off + (t - MT)];
    __syncthreads();

    // ---- gather + fp32->bf16 convert into A_lds ----
    // seg 0: x[dst] -> k [0,128)
    #pragma unroll
    for (int it = 0; it < 8; ++it) {
        int idx = it * 256 + t;
        int e = idx >> 5, kq = idx & 31;              // kq: float4 within row
        float4 v = ((const float4*)(x + (size_t)dst_lds[e] * DD))[kq];
        int g = kq >> 1;
        int col = ((g & ~7) | ((g & 7) ^ (e & 7))) * 8 + (kq & 1) * 4;
        ushort4 pk; pk.x = f2bf(v.x); pk.y = f2bf(v.y); pk.z = f2bf(v.z); pk.w = f2bf(v.w);
        *((ushort4*)&A_lds[e * ZDIM + col]) = pk;
    }
    // seg 1: x[src] -> k [128,256)
    #pragma unroll
    for (int it = 0; it < 8; ++it) {
        int idx = it * 256 + t;
        int e = idx >> 5, kq = idx & 31;
        float4 v = ((const float4*)(x + (size_t)src_lds[e] * DD))[kq];
        int g = 16 + (kq >> 1);
        int col = ((g & ~7) | ((g & 7) ^ (e & 7))) * 8 + (kq & 1) * 4;
        ushort4 pk; pk.x = f2bf(v.x); pk.y = f2bf(v.y); pk.z = f2bf(v.z); pk.w = f2bf(v.w);
        *((ushort4*)&A_lds[e * ZDIM + col]) = pk;
    }
    // seg 2: edge_attr -> k [256,320)
    #pragma unroll
    for (int it = 0; it < 4; ++it) {
        int idx = it * 256 + t;
        int e = idx >> 4, kq = idx & 15;
        float4 v = ((const float4*)(ea + (size_t)(m_off + e) * DE))[kq];
        int g = 32 + (kq >> 1);
        int col = ((g & ~7) | ((g & 7) ^ (e & 7))) * 8 + (kq & 1) * 4;
        ushort4 pk; pk.x = f2bf(v.x); pk.y = f2bf(v.y); pk.z = f2bf(v.z); pk.w = f2bf(v.w);
        *((ushort4*)&A_lds[e * ZDIM + col]) = pk;
    }

    f32x4 acc[4][4] = {};   // [m-tile][u]: u=0,1 f-cols; u=2,3 s-cols
    const int nt0 = 2 * w;

    for (int kc = 0; kc < 5; ++kc) {
        __syncthreads();
        // stage B chunk: Wt[n][kc*64 .. +64) -> B_lds (swizzled)
        #pragma unroll
        for (int it = 0; it < 8; ++it) {
            int idx = it * 256 + t;
            int n = idx >> 3, kb = idx & 7;
            int4 v = *((const int4*)(Wt + n * ZDIM + kc * 64 + kb * 8));
            *((int4*)&B_lds[n * 64 + (kb ^ (n & 7)) * 8]) = v;
        }
        __syncthreads();

        #pragma unroll
        for (int ks = 0; ks < 2; ++ks) {
            bf16x8 af[4], bfr[4];
            #pragma unroll
            for (int i = 0; i < 4; ++i) {
                int m = i * 16 + l15;
                int g = 8 * kc + 4 * ks + quad;
                int col = ((g & ~7) | ((g & 7) ^ (l15 & 7))) * 8;
                af[i] = *((const bf16x8*)&A_lds[m * ZDIM + col]);
            }
            #pragma unroll
            for (int u = 0; u < 4; ++u) {
                int nt = nt0 + ((u < 2) ? u : (6 + u));   // {nt0, nt0+1, nt0+8, nt0+9}
                int n = nt * 16 + l15;
                int col = ((4 * ks + quad) ^ (l15 & 7)) * 8;
                bfr[u] = *((const bf16x8*)&B_lds[n * 64 + col]);
            }
            #pragma unroll
            for (int i = 0; i < 4; ++i)
                #pragma unroll
                for (int u = 0; u < 4; ++u)
                    acc[i][u] = __builtin_amdgcn_mfma_f32_16x16x32_bf16(
                        af[i], bfr[u], acc[i][u], 0, 0, 0);
        }
    }

    // ---- epilogue: gate + scatter-add ----
    const int c0 = 32 * w + l15;
    const int c1 = c0 + 16;
    const float bf0 = bf_[c0], bs0 = bs_[c0];
    const float bf1 = bf_[c1], bs1 = bs_[c1];

    #pragma unroll
    for (int i = 0; i < 4; ++i) {
        #pragma unroll
        for (int j = 0; j < 4; ++j) {
            int e = i * 16 + quad * 4 + j;
            float* op = out + (size_t)dst_lds[e] * DD;
            float f0 = acc[i][0][j] + bf0;
            float s0 = acc[i][2][j] + bs0;
            float m0 = (1.0f / (1.0f + __expf(-f0))) *
                       (fmaxf(s0, 0.0f) + log1pf(__expf(-fabsf(s0))));
            atomicAdd(op + c0, m0);
            float f1 = acc[i][1][j] + bf1;
            float s1 = acc[i][3][j] + bs1;
            float m1 = (1.0f / (1.0f + __expf(-f1))) *
                       (fmaxf(s1, 0.0f) + log1pf(__expf(-fabsf(s1))));
            atomicAdd(op + c1, m1);
        }
    }
}

__global__ void relu_kernel(float* __restrict__ out) {
    int id = blockIdx.x * 256 + threadIdx.x;
    if (id < NN * DD / 4) {
        float4 v = ((float4*)out)[id];
        v.x = fmaxf(v.x, 0.0f); v.y = fmaxf(v.y, 0.0f);
        v.z = fmaxf(v.z, 0.0f); v.w = fmaxf(v.w, 0.0f);
        ((float4*)out)[id] = v;
    }
}

extern "C" void kernel_launch(void* const* d_in, const int* in_sizes, int n_in,
                              void* d_out, int out_size, void* d_ws, size_t ws_size,
                              hipStream_t stream) {
    (void)in_sizes; (void)n_in; (void)out_size; (void)ws_size;
    const float* x   = (const float*)d_in[0];
    const int*   ei  = (const int*)d_in[1];
    const float* ea  = (const float*)d_in[2];
    const float* W_f = (const float*)d_in[3];
    const float* b_f = (const float*)d_in[4];
    const float* W_s = (const float*)d_in[5];
    const float* b_s = (const float*)d_in[6];
    float* out = (float*)d_out;
    unsigned short* Wt = (unsigned short*)d_ws;   // 256*320 bf16 = 160 KB

    prep_kernel<<<6250, 256, 0, stream>>>(x, W_f, W_s, Wt, out);
    edge_kernel<<<E_TOTAL / MT, 256, 0, stream>>>(x, ei, ea, Wt, b_f, b_s, out);
    relu_kernel<<<6250, 256, 0, stream>>>(out);
}

// Round 2
// 665.026 us; speedup vs baseline: 1.1212x; 1.1212x over previous
//
#include <hip/hip_runtime.h>
#include <hip/hip_bf16.h>

#define E_TOTAL   800000
#define NN        50000
#define DD        128
#define DE        64
#define ZDIM      320
#define MT        64

typedef short bf16x8 __attribute__((ext_vector_type(8)));
typedef float f32x4  __attribute__((ext_vector_type(4)));

__device__ __forceinline__ unsigned short f2bf(float f) {
    union { float f; unsigned int u; } v; v.f = f;
    unsigned int u = v.u;
    return (unsigned short)((u + 0x7fffu + ((u >> 16) & 1u)) >> 16);
}

// packed f32x2 -> bf16x2 (RNE); on gfx950 lowers to v_cvt_pk_bf16_f32
__device__ __forceinline__ unsigned pkbf2(float a, float b) {
    __hip_bfloat162 h = __float22bfloat162_rn(make_float2(a, b));
    unsigned u; __builtin_memcpy(&u, &h, 4); return u;
}

__device__ __forceinline__ uint2 pkbf4(float4 v) {
    uint2 r; r.x = pkbf2(v.x, v.y); r.y = pkbf2(v.z, v.w); return r;
}

__device__ __forceinline__ float fast_rcp(float x) {
#if __has_builtin(__builtin_amdgcn_rcpf)
    return __builtin_amdgcn_rcpf(x);
#else
    return 1.0f / x;
#endif
}

// out <- x ; Wt[n][k] = bf16(concat(W_f, W_s)^T)
__global__ void prep_kernel(const float* __restrict__ x,
                            const float* __restrict__ W_f,
                            const float* __restrict__ W_s,
                            unsigned short* __restrict__ Wt,
                            float* __restrict__ out) {
    int id = blockIdx.x * 256 + threadIdx.x;
    if (id < NN * DD / 4)
        ((float4*)out)[id] = ((const float4*)x)[id];
    if (id < 2 * DD * ZDIM) {
        int n = id / ZDIM, k = id - n * ZDIM;
        float wv = (n < DD) ? W_f[k * DD + n] : W_s[k * DD + (n - DD)];
        Wt[n * ZDIM + k] = f2bf(wv);
    }
}

// Fused gather + dual-GEMM + gated activation + scatter-add.
// Block: 256 thr (4 waves), 64 edges, N=256 (f||s), K=320.
// A (edge features) staged in LDS with XOR swizzle (verified conflict-free R1).
// B (weights) loaded per-fragment DIRECTLY from global Wt (L2-resident):
// the 16x16x32 B-fragment is a contiguous bf16x8 of row-major Wt.
__global__ __launch_bounds__(256, 3)
void edge_kernel(const float* __restrict__ x,
                 const int* __restrict__ ei,
                 const float* __restrict__ ea,
                 const unsigned short* __restrict__ Wt,
                 const float* __restrict__ bf_,
                 const float* __restrict__ bs_,
                 float* __restrict__ out) {
    __shared__ unsigned short A_lds[MT * ZDIM];   // 40960 B
    __shared__ int dst_lds[MT];
    __shared__ int src_lds[MT];

    const int t = threadIdx.x;
    const int m_off = blockIdx.x * MT;
    const int lane = t & 63;
    const int w = t >> 6;
    const int l15 = lane & 15;
    const int quad = lane >> 4;

    if (t < MT) dst_lds[t] = ei[E_TOTAL + m_off + t];
    else if (t < 2 * MT) src_lds[t - MT] = ei[m_off + (t - MT)];
    __syncthreads();

    // ---- gather + packed fp32->bf16 convert into A_lds ----
    // seg 2 first: edge_attr (HBM stream) -> k [256,320)
    #pragma unroll
    for (int it = 0; it < 4; ++it) {
        int idx = it * 256 + t;
        int e = idx >> 4, kq = idx & 15;
        float4 v = ((const float4*)(ea + (size_t)(m_off + e) * DE))[kq];
        int g = 32 + (kq >> 1);
        int col = ((g & ~7) | ((g & 7) ^ (e & 7))) * 8 + (kq & 1) * 4;
        *((uint2*)&A_lds[e * ZDIM + col]) = pkbf4(v);
    }
    // seg 0: x[dst] -> k [0,128)
    #pragma unroll
    for (int it = 0; it < 8; ++it) {
        int idx = it * 256 + t;
        int e = idx >> 5, kq = idx & 31;
        float4 v = ((const float4*)(x + (size_t)dst_lds[e] * DD))[kq];
        int g = kq >> 1;
        int col = ((g & ~7) | ((g & 7) ^ (e & 7))) * 8 + (kq & 1) * 4;
        *((uint2*)&A_lds[e * ZDIM + col]) = pkbf4(v);
    }
    // seg 1: x[src] -> k [128,256)
    #pragma unroll
    for (int it = 0; it < 8; ++it) {
        int idx = it * 256 + t;
        int e = idx >> 5, kq = idx & 31;
        float4 v = ((const float4*)(x + (size_t)src_lds[e] * DD))[kq];
        int g = 16 + (kq >> 1);
        int col = ((g & ~7) | ((g & 7) ^ (e & 7))) * 8 + (kq & 1) * 4;
        *((uint2*)&A_lds[e * ZDIM + col]) = pkbf4(v);
    }

    f32x4 acc[4][4] = {};   // [m-tile][u]: u=0,1 f-cols; u=2,3 s-cols
    const int nt0 = 2 * w;

    // B fragment base pointers (global, L2-hot); per-(kc,ks) offsets are
    // compile-time immediates.
    const unsigned short* Bp[4];
    #pragma unroll
    for (int u = 0; u < 4; ++u) {
        int nt = nt0 + ((u < 2) ? u : (6 + u));   // {nt0, nt0+1, nt0+8, nt0+9}
        Bp[u] = Wt + (size_t)(nt * 16 + l15) * ZDIM + quad * 8;
    }

    __syncthreads();   // A_lds ready; K-loop is barrier-free

    #pragma unroll
    for (int kc = 0; kc < 5; ++kc) {
        #pragma unroll
        for (int ks = 0; ks < 2; ++ks) {
            bf16x8 af[4], bfr[4];
            #pragma unroll
            for (int i = 0; i < 4; ++i) {
                int m = i * 16 + l15;
                int g = 8 * kc + 4 * ks + quad;
                int col = ((g & ~7) | ((g & 7) ^ (l15 & 7))) * 8;
                af[i] = *((const bf16x8*)&A_lds[m * ZDIM + col]);
            }
            #pragma unroll
            for (int u = 0; u < 4; ++u)
                bfr[u] = *((const bf16x8*)(Bp[u] + kc * 64 + ks * 32));
            #pragma unroll
            for (int i = 0; i < 4; ++i)
                #pragma unroll
                for (int u = 0; u < 4; ++u)
                    acc[i][u] = __builtin_amdgcn_mfma_f32_16x16x32_bf16(
                        af[i], bfr[u], acc[i][u], 0, 0, 0);
        }
    }

    // ---- epilogue: gate + scatter-add (fast native math) ----
    const int c0 = 32 * w + l15;
    const int c1 = c0 + 16;
    const float bf0 = bf_[c0], bs0 = bs_[c0];
    const float bf1 = bf_[c1], bs1 = bs_[c1];

    #pragma unroll
    for (int i = 0; i < 4; ++i) {
        #pragma unroll
        for (int j = 0; j < 4; ++j) {
            int e = i * 16 + quad * 4 + j;
            float* op = out + (size_t)dst_lds[e] * DD;
            float f0 = acc[i][0][j] + bf0;
            float s0 = acc[i][2][j] + bs0;
            float m0 = fast_rcp(1.0f + __expf(-f0)) *
                       (fmaxf(s0, 0.0f) + __logf(1.0f + __expf(-fabsf(s0))));
            atomicAdd(op + c0, m0);
            float f1 = acc[i][1][j] + bf1;
            float s1 = acc[i][3][j] + bs1;
            float m1 = fast_rcp(1.0f + __expf(-f1)) *
                       (fmaxf(s1, 0.0f) + __logf(1.0f + __expf(-fabsf(s1))));
            atomicAdd(op + c1, m1);
        }
    }
}

__global__ void relu_kernel(float* __restrict__ out) {
    int id = blockIdx.x * 256 + threadIdx.x;
    if (id < NN * DD / 4) {
        float4 v = ((float4*)out)[id];
        v.x = fmaxf(v.x, 0.0f); v.y = fmaxf(v.y, 0.0f);
        v.z = fmaxf(v.z, 0.0f); v.w = fmaxf(v.w, 0.0f);
        ((float4*)out)[id] = v;
    }
}

extern "C" void kernel_launch(void* const* d_in, const int* in_sizes, int n_in,
                              void* d_out, int out_size, void* d_ws, size_t ws_size,
                              hipStream_t stream) {
    (void)in_sizes; (void)n_in; (void)out_size; (void)ws_size;
    const float* x   = (const float*)d_in[0];
    const int*   ei  = (const int*)d_in[1];
    const float* ea  = (const float*)d_in[2];
    const float* W_f = (const float*)d_in[3];
    const float* b_f = (const float*)d_in[4];
    const float* W_s = (const float*)d_in[5];
    const float* b_s = (const float*)d_in[6];
    float* out = (float*)d_out;
    unsigned short* Wt = (unsigned short*)d_ws;   // 256*320 bf16 = 160 KB

    prep_kernel<<<6250, 256, 0, stream>>>(x, W_f, W_s, Wt, out);
    edge_kernel<<<E_TOTAL / MT, 256, 0, stream>>>(x, ei, ea, Wt, b_f, b_s, out);
    relu_kernel<<<6250, 256, 0, stream>>>(out);
}